// Round 3
// baseline (312.417 us; speedup 1.0000x reference)
//
#include <hip/hip_runtime.h>

// ---------------------------------------------------------------------------
// LSTransformerEncoderLayer on MI355X (gfx950), round 2.
// Round-2 change: new gemm256 — 8-phase counted-vmcnt schedule (T3+T4),
// 256x256 tile, 8 waves, raw s_barrier, vmcnt(4), setprio (T5), XOR-swizzled
// LDS (T2), XCD swizzle (T1) — used for QKV and FFN1. gemm_bt keeps proj and
// FFN2 (N=1024: 256-tile grid would be 128 blocks = half chip) + T1 swizzle.
// attn/LN/wconv unchanged from round 1.
// ---------------------------------------------------------------------------

using f32x4  = __attribute__((ext_vector_type(4))) float;
using f32x16 = __attribute__((ext_vector_type(16))) float;
using s16x8  = __attribute__((ext_vector_type(8))) short;   // 8 bf16 in 4 VGPRs
using i32x4  = __attribute__((ext_vector_type(4))) int;

__device__ __forceinline__ unsigned short f2bf(float f) {
    unsigned x = __builtin_bit_cast(unsigned, f);
    return (unsigned short)((x + 0x7fffu + ((x >> 16) & 1u)) >> 16);  // RNE
}

#define GLL16(gptr, lptr)                                                     \
    __builtin_amdgcn_global_load_lds(                                         \
        (const __attribute__((address_space(1))) void*)(gptr),                \
        (__attribute__((address_space(3))) void*)(lptr), 16, 0, 0)

// ---------------------------------------------------------------------------
// Weight convert: fp32 -> bf16, all four weights in one launch.
// ---------------------------------------------------------------------------
__global__ __launch_bounds__(256) void wconv_kernel(
    const float* __restrict__ w0, const float* __restrict__ w1,
    const float* __restrict__ w2, const float* __restrict__ w3,
    unsigned short* __restrict__ o0, unsigned short* __restrict__ o1,
    unsigned short* __restrict__ o2, unsigned short* __restrict__ o3) {
    long idx = (long)blockIdx.x * 256 + threadIdx.x;  // float4 index
    const float* src;
    unsigned short* dst;
    long rel;
    if (idx < 786432L)        { src = w0; dst = o0; rel = idx; }
    else if (idx < 1048576L)  { src = w1; dst = o1; rel = idx - 786432L; }
    else if (idx < 2097152L)  { src = w2; dst = o2; rel = idx - 1048576L; }
    else                      { src = w3; dst = o3; rel = idx - 2097152L; }
    float4 v = *(const float4*)(src + rel * 4);
    ushort4 o;
    o.x = f2bf(v.x); o.y = f2bf(v.y); o.z = f2bf(v.z); o.w = f2bf(v.w);
    *(ushort4*)(dst + rel * 4) = o;
}

// ---------------------------------------------------------------------------
// LayerNorm: one block per row of 1024 fp32, 256 threads (one float4 each).
// ---------------------------------------------------------------------------
__global__ __launch_bounds__(256) void ln_kernel(
    const float* __restrict__ x, const float* __restrict__ gw,
    const float* __restrict__ bw, unsigned short* __restrict__ y) {
    __shared__ float rbuf[8];
    const int row = blockIdx.x;
    const int t = threadIdx.x;
    const float* xr = x + (size_t)row * 1024;
    float4 v = *(const float4*)(xr + t * 4);
    float s  = v.x + v.y + v.z + v.w;
    float ss = v.x * v.x + v.y * v.y + v.z * v.z + v.w * v.w;
#pragma unroll
    for (int sh = 1; sh < 64; sh <<= 1) {
        s  += __shfl_xor(s, sh, 64);
        ss += __shfl_xor(ss, sh, 64);
    }
    int w = t >> 6;
    if ((t & 63) == 0) { rbuf[w * 2] = s; rbuf[w * 2 + 1] = ss; }
    __syncthreads();
    s  = rbuf[0] + rbuf[2] + rbuf[4] + rbuf[6];
    ss = rbuf[1] + rbuf[3] + rbuf[5] + rbuf[7];
    float mu  = s * (1.f / 1024.f);
    float var = ss * (1.f / 1024.f) - mu * mu;
    float rs  = rsqrtf(var + 1e-5f);
    float4 gv = *(const float4*)(gw + t * 4);
    float4 bv = *(const float4*)(bw + t * 4);
    ushort4 o;
    o.x = f2bf((v.x - mu) * rs * gv.x + bv.x);
    o.y = f2bf((v.y - mu) * rs * gv.y + bv.y);
    o.z = f2bf((v.z - mu) * rs * gv.z + bv.z);
    o.w = f2bf((v.w - mu) * rs * gv.w + bv.w);
    *(ushort4*)(y + (size_t)row * 1024 + t * 4) = o;
}

// ---------------------------------------------------------------------------
// gemm_bt (m97 2-barrier structure) + T1 XCD swizzle. Used for proj & FFN2.
// C[M,N] = A[M,K] * B[N,K]^T (+bias, +resid, relu, out bf16/f32).
// ---------------------------------------------------------------------------
template <bool RELU, bool RESID, bool OUT_BF16>
__global__ __launch_bounds__(256, 2) void gemm_bt(
    const unsigned short* __restrict__ A, const unsigned short* __restrict__ Bw,
    const float* __restrict__ bias, const float* __restrict__ resid,
    void* __restrict__ Cout, int M, int N, int K) {
    __shared__ char smem[2 * 128 * 64 * 2];
    char* As = smem;
    char* Bs = smem + 128 * 64 * 2;

    const int tid = threadIdx.x;
    const int lane = tid & 63;
    const int w = tid >> 6;
    const int wr = w >> 1, wc = w & 1;
    const int g = lane >> 4;
    const int fr = lane & 15;
    // T1: bijective XCD-chunked swizzle (nwg % 8 == 0 for all our grids)
    const int nwg = gridDim.x * gridDim.y;
    const int L = blockIdx.y * gridDim.x + blockIdx.x;
    const int swz = (L & 7) * (nwg >> 3) + (L >> 3);
    const int m0 = (swz / gridDim.x) * 128;
    const int n0 = (swz % gridDim.x) * 128;

    f32x4 acc[4][4] = {};

    for (int kt = 0; kt < K; kt += 64) {
#pragma unroll
        for (int c = 0; c < 4; ++c) {
            int lin = (c * 256 + tid) * 16;        // linear LDS byte (dest)
            int row = lin >> 7;                    // 128 B per row
            int Lb = lin ^ ((row & 7) << 4);       // logical byte (source)
            int colb = Lb & 127;
            const char* ga = (const char*)A + ((size_t)(m0 + row) * K + kt) * 2 + colb;
            const char* gb = (const char*)Bw + ((size_t)(n0 + row) * K + kt) * 2 + colb;
            GLL16(ga, As + lin);
            GLL16(gb, Bs + lin);
        }
        __syncthreads();
#pragma unroll
        for (int ks = 0; ks < 2; ++ks) {
            s16x8 af[4], bf[4];
#pragma unroll
            for (int mi = 0; mi < 4; ++mi) {
                int row = wr * 64 + mi * 16 + fr;
                int off = (row << 7) + ((ks * 64 + g * 16) ^ ((row & 7) << 4));
                af[mi] = *(const s16x8*)(As + off);
            }
#pragma unroll
            for (int ni = 0; ni < 4; ++ni) {
                int row = wc * 64 + ni * 16 + fr;
                int off = (row << 7) + ((ks * 64 + g * 16) ^ ((row & 7) << 4));
                bf[ni] = *(const s16x8*)(Bs + off);
            }
#pragma unroll
            for (int mi = 0; mi < 4; ++mi)
#pragma unroll
                for (int ni = 0; ni < 4; ++ni)
                    acc[mi][ni] = __builtin_amdgcn_mfma_f32_16x16x32_bf16(
                        af[mi], bf[ni], acc[mi][ni], 0, 0, 0);
        }
        __syncthreads();
    }

    float bv[4];
#pragma unroll
    for (int ni = 0; ni < 4; ++ni) bv[ni] = bias[n0 + wc * 64 + ni * 16 + fr];
#pragma unroll
    for (int mi = 0; mi < 4; ++mi) {
#pragma unroll
        for (int r = 0; r < 4; ++r) {
            int row = m0 + wr * 64 + mi * 16 + g * 4 + r;
#pragma unroll
            for (int ni = 0; ni < 4; ++ni) {
                int col = n0 + wc * 64 + ni * 16 + fr;
                float v = acc[mi][ni][r] + bv[ni];
                if (RELU) v = v > 0.f ? v : 0.f;
                if (RESID) v += resid[(size_t)row * N + col];
                if (OUT_BF16)
                    ((unsigned short*)Cout)[(size_t)row * N + col] = f2bf(v);
                else
                    ((float*)Cout)[(size_t)row * N + col] = v;
            }
        }
    }
}

// ---------------------------------------------------------------------------
// gemm256: 8-phase counted-vmcnt GEMM (T1+T2+T3+T4+T5). C = A[M,K]*B[N,K]^T.
// 256x256 tile, BK=64, 512 thr = 8 waves (2M x 4N), per-wave 128x64 out as
// interleaved halves: wave(wm,wn) rows {ha*128+wm*64+mi2*16}, cols
// {hb*128+wn*32+ni2*16}. LDS 128KB: A[2buf][256][64], B same @+65536,
// XOR-swz ((row&7)<<4). Staging: half-tile (128 rows) per phase, order
// [A0,B0,B1,A1] for tile t+1 during tile t; phase p computes (ha=p>>1,
// hb=p&1) quadrant = 16 MFMA. vmcnt(4) per phase (2 halves in flight),
// raw s_barrier (no vmcnt drain). Ledger verified: every half staged >=2
// phases (+vmcnt+barrier) before first ds_read.
// ---------------------------------------------------------------------------
template <bool RELU, bool OUT_BF16>
__global__ __launch_bounds__(512, 2) void gemm256(
    const unsigned short* __restrict__ A, const unsigned short* __restrict__ Bw,
    const float* __restrict__ bias, void* __restrict__ Cout,
    int M, int N, int K) {
    extern __shared__ char lds[];

    const int tid = threadIdx.x;
    const int lane = tid & 63;
    const int w = tid >> 6;
    const int wm = w >> 2, wn = w & 3;
    const int g = lane >> 4, fr = lane & 15;

    // T1 XCD swizzle (nwg % 8 == 0: 384 and 512)
    const int nwg = gridDim.x * gridDim.y;
    const int L = blockIdx.y * gridDim.x + blockIdx.x;
    const int swz = (L & 7) * (nwg >> 3) + (L >> 3);
    const int m0 = (swz / gridDim.x) * 256;
    const int n0 = (swz % gridDim.x) * 256;

    const int NT = K >> 6;

    // staging: one half-tile (128 rows x 64 cols bf16 = 16KB) = 2 GLL/thread
    auto stageA = [&](int t, int h) {
        char* dst = lds + (t & 1) * 32768 + h * 16384;
#pragma unroll
        for (int c2 = 0; c2 < 2; ++c2) {
            int lin = (c2 * 512 + tid) * 16;
            int row = lin >> 7;
            int colb = (lin & 127) ^ ((row & 7) << 4);
            GLL16((const char*)A + ((size_t)(m0 + h * 128 + row) * K + t * 64) * 2 + colb,
                  dst + lin);
        }
    };
    auto stageB = [&](int t, int h) {
        char* dst = lds + 65536 + (t & 1) * 32768 + h * 16384;
#pragma unroll
        for (int c2 = 0; c2 < 2; ++c2) {
            int lin = (c2 * 512 + tid) * 16;
            int row = lin >> 7;
            int colb = (lin & 127) ^ ((row & 7) << 4);
            GLL16((const char*)Bw + ((size_t)(n0 + h * 128 + row) * K + t * 64) * 2 + colb,
                  dst + lin);
        }
    };

    f32x4 acc[2][4][2][2] = {};  // [ha][mi2][hb][ni2]
    s16x8 af[4][2];              // current A-half fragments [mi2][ks]
    s16x8 bf[2][2];              // current B-half fragments [ni2][ks]

    // prologue: tile 0, order A0,B0,B1,A1; allow 2 halves (4 loads) in flight
    stageA(0, 0); stageB(0, 0); stageB(0, 1); stageA(0, 1);
    asm volatile("s_waitcnt vmcnt(4)" ::: "memory");
    __builtin_amdgcn_s_barrier();

    for (int t = 0; t < NT; ++t) {
        char* Ab = lds + (t & 1) * 32768;
        char* Bb = lds + 65536 + (t & 1) * 32768;
        const bool more = (t + 1 < NT);
#pragma unroll
        for (int p = 0; p < 4; ++p) {
            const int ha = p >> 1, hb = p & 1;
            // stage one half of tile t+1: order A0,B0,B1,A1
            if (more) {
                if (p == 0)      stageA(t + 1, 0);
                else if (p == 1) stageB(t + 1, 0);
                else if (p == 2) stageB(t + 1, 1);
                else             stageA(t + 1, 1);
            }
            // ds_read fragments for this quadrant
            if ((p & 1) == 0) {  // new A-half at p=0,2
#pragma unroll
                for (int mi2 = 0; mi2 < 4; ++mi2) {
                    int row = ha * 128 + wm * 64 + mi2 * 16 + fr;
#pragma unroll
                    for (int ks = 0; ks < 2; ++ks)
                        af[mi2][ks] = *(const s16x8*)(Ab + (row << 7) +
                                       ((ks * 64 + g * 16) ^ ((row & 7) << 4)));
                }
            }
#pragma unroll
            for (int ni2 = 0; ni2 < 2; ++ni2) {
                int row = hb * 128 + wn * 32 + ni2 * 16 + fr;
#pragma unroll
                for (int ks = 0; ks < 2; ++ks)
                    bf[ni2][ks] = *(const s16x8*)(Bb + (row << 7) +
                                   ((ks * 64 + g * 16) ^ ((row & 7) << 4)));
            }
            asm volatile("s_waitcnt vmcnt(4)" ::: "memory");
            __builtin_amdgcn_s_barrier();
            asm volatile("s_waitcnt lgkmcnt(0)" ::: "memory");
            __builtin_amdgcn_sched_barrier(0);
            __builtin_amdgcn_s_setprio(1);
#pragma unroll
            for (int mi2 = 0; mi2 < 4; ++mi2)
#pragma unroll
                for (int ni2 = 0; ni2 < 2; ++ni2)
#pragma unroll
                    for (int ks = 0; ks < 2; ++ks)
                        acc[ha][mi2][hb][ni2] = __builtin_amdgcn_mfma_f32_16x16x32_bf16(
                            af[mi2][ks], bf[ni2][ks], acc[ha][mi2][hb][ni2], 0, 0, 0);
            __builtin_amdgcn_s_setprio(0);
            __builtin_amdgcn_s_barrier();
        }
    }

    // epilogue: bias (+relu), store
#pragma unroll
    for (int ha = 0; ha < 2; ++ha)
#pragma unroll
        for (int mi2 = 0; mi2 < 4; ++mi2)
#pragma unroll
            for (int r = 0; r < 4; ++r) {
                int row = m0 + ha * 128 + wm * 64 + mi2 * 16 + g * 4 + r;
#pragma unroll
                for (int hb = 0; hb < 2; ++hb)
#pragma unroll
                    for (int ni2 = 0; ni2 < 2; ++ni2) {
                        int col = n0 + hb * 128 + wn * 32 + ni2 * 16 + fr;
                        float v = acc[ha][mi2][hb][ni2][r] + bias[col];
                        if (RELU) v = v > 0.f ? v : 0.f;
                        if (OUT_BF16)
                            ((unsigned short*)Cout)[(size_t)row * N + col] = f2bf(v);
                        else
                            ((float*)Cout)[(size_t)row * N + col] = v;
                    }
            }
}

// ---------------------------------------------------------------------------
// Fused attention v2 (unchanged from round 1).
// ---------------------------------------------------------------------------
__global__ __launch_bounds__(512, 2) void attn_kernel(
    const unsigned short* __restrict__ qkv, const float* __restrict__ mask,
    unsigned short* __restrict__ ctx) {
    extern __shared__ char smem[];

    const int tid = threadIdx.x;
    const int lane = tid & 63;
    const int w = tid >> 6;
    const int l31 = lane & 31;
    const int hi = lane >> 5;
    const int bh = blockIdx.x >> 1;
    const int b = bh >> 4, h = bh & 15;
    const int qt = (blockIdx.x & 1) * 256 + w * 32;

    const size_t rstr = 3072;
    const unsigned short* qbase = qkv + (size_t)b * 512 * rstr + h * 64;
    const unsigned short* kbase = qbase + 1024;
    const unsigned short* vbase = qbase + 2048;
    const float* mrow = mask + b * 512;

    s16x8 qf[4];
#pragma unroll
    for (int kc = 0; kc < 4; ++kc)
        qf[kc] = *(const s16x8*)(qbase + (size_t)(qt + l31) * rstr + kc * 16 + hi * 8);

    f32x16 O0 = {}, O1 = {};
    float m = -3e38f, l = 0.f;
    const int bpbase = 36 * hi * 4;

    auto stage = [&](int kt, int bufsel) {
        char* Kb = smem + bufsel * 16384;
        char* Vb = smem + 32768 + bufsel * 16384;
#pragma unroll
        for (int c = 0; c < 2; ++c) {
            int lin = (c * 512 + tid) * 16;
            int row = lin >> 7;
            int colb = (lin & 127) ^ ((row & 7) << 4);
            GLL16((const char*)kbase + (size_t)(kt * 128 + row) * rstr * 2 + colb,
                  Kb + lin);
        }
        int s = tid & 127, dg = tid >> 7;
        const unsigned short* vsrc = vbase + (size_t)(kt * 128 + s) * rstr + dg * 16;
        union { i32x4 v; unsigned short u[8]; } v0, v1;
        v0.v = *(const i32x4*)vsrc;
        v1.v = *(const i32x4*)(vsrc + 8);
#pragma unroll
        for (int j = 0; j < 8; ++j) {
            int d = dg * 16 + j;
            *(unsigned short*)(Vb + d * 256 + ((s * 2) ^ ((d & 15) << 4))) = v0.u[j];
        }
#pragma unroll
        for (int j = 0; j < 8; ++j) {
            int d = dg * 16 + 8 + j;
            *(unsigned short*)(Vb + d * 256 + ((s * 2) ^ ((d & 15) << 4))) = v1.u[j];
        }
    };

    const float C   = 0.18033688f;   // log2e / sqrt(64)
    const float L2E = 1.44269504f;

    stage(0, 0);
    __syncthreads();

    for (int kt = 0; kt < 4; ++kt) {
        const int cur = kt & 1;
        if (kt < 3) stage(kt + 1, cur ^ 1);
        char* Kb = smem + cur * 16384;
        char* Vb = smem + 32768 + cur * 16384;
        const int swzk = (l31 & 7) << 4;

        f32x16 sc[4];
#pragma unroll
        for (int t = 0; t < 4; ++t) {
            f32x16 a = {};
#pragma unroll
            for (int kc = 0; kc < 4; ++kc) {
                s16x8 kf = *(const s16x8*)(Kb + (32 * t + l31) * 128 +
                                           ((kc * 32 + hi * 16) ^ swzk));
                a = __builtin_amdgcn_mfma_f32_32x32x16_bf16(kf, qf[kc], a, 0, 0, 0);
            }
            sc[t] = a;
        }

        float tm = -3e38f;
#pragma unroll
        for (int t = 0; t < 4; ++t) {
#pragma unroll
            for (int k2 = 0; k2 < 4; ++k2) {
                f32x4 mk = *(const f32x4*)(mrow + kt * 128 + 32 * t + 8 * k2 + 4 * hi);
#pragma unroll
                for (int i = 0; i < 4; ++i) {
                    float v = sc[t][4 * k2 + i] * C + mk[i] * L2E;
                    sc[t][4 * k2 + i] = v;
                    tm = fmaxf(tm, v);
                }
            }
        }
        tm = fmaxf(tm, __shfl_xor(tm, 32, 64));

        if (__any(tm > m + 11.0f)) {
            float mn = fmaxf(m, tm);
            float fac = exp2f(m - mn);
            m = mn;
            l *= fac;
            int fi = __float_as_int(fac);
#pragma unroll
            for (int r = 0; r < 16; ++r) {
                int q2 = (r & 3) + 8 * (r >> 2);
                float fq = __int_as_float(
                    __builtin_amdgcn_ds_bpermute(bpbase + q2 * 4, fi));
                O0[r] *= fq;
                O1[r] *= fq;
            }
        }

        float ts = 0.f;
#pragma unroll
        for (int t = 0; t < 4; ++t)
#pragma unroll
            for (int r = 0; r < 16; ++r) {
                float p = exp2f(sc[t][r] - m);
                sc[t][r] = p;
                ts += p;
            }
        ts += __shfl_xor(ts, 32, 64);
        l += ts;

        unsigned pk01[4][4], pk23[4][4];
#pragma unroll
        for (int t = 0; t < 4; ++t)
#pragma unroll
            for (int k = 0; k < 4; ++k) {
                unsigned r0, r1;
                asm("v_cvt_pk_bf16_f32 %0, %1, %2"
                    : "=v"(r0) : "v"(sc[t][4 * k]), "v"(sc[t][4 * k + 1]));
                asm("v_cvt_pk_bf16_f32 %0, %1, %2"
                    : "=v"(r1) : "v"(sc[t][4 * k + 2]), "v"(sc[t][4 * k + 3]));
                pk01[t][k] = r0;
                pk23[t][k] = r1;
            }

#pragma unroll
        for (int t = 0; t < 4; ++t)
#pragma unroll
            for (int cc = 0; cc < 2; ++cc) {
                unsigned a0 = pk01[t][2 * cc], b0 = pk01[t][2 * cc + 1];
                unsigned c0 = pk23[t][2 * cc], d0 = pk23[t][2 * cc + 1];
                asm("v_permlane32_swap_b32 %0, %1" : "+v"(a0), "+v"(b0));
                asm("v_permlane32_swap_b32 %0, %1" : "+v"(c0), "+v"(d0));
                union { unsigned u[4]; s16x8 v; } pf;
                pf.u[0] = a0;
                pf.u[1] = c0;
                pf.u[2] = b0;
                pf.u[3] = d0;
                const int kc = 2 * t + cc;
                {
                    int row = l31;
                    s16x8 vf = *(const s16x8*)(Vb + row * 256 +
                               ((kc * 32 + hi * 16) ^ ((row & 15) << 4)));
                    O0 = __builtin_amdgcn_mfma_f32_32x32x16_bf16(pf.v, vf, O0, 0, 0, 0);
                }
                {
                    int row = 32 + l31;
                    s16x8 vf = *(const s16x8*)(Vb + row * 256 +
                               ((kc * 32 + hi * 16) ^ ((row & 15) << 4)));
                    O1 = __builtin_amdgcn_mfma_f32_32x32x16_bf16(pf.v, vf, O1, 0, 0, 0);
                }
            }
        __syncthreads();
    }

    const int li = __float_as_int(l);
#pragma unroll
    for (int r = 0; r < 16; ++r) {
        int q2 = (r & 3) + 8 * (r >> 2);
        float lq = __int_as_float(__builtin_amdgcn_ds_bpermute(bpbase + q2 * 4, li));
        float inv = 1.f / lq;
        size_t rowg = (size_t)(b * 512 + qt + q2 + 4 * hi) * 1024 + h * 64;
        ctx[rowg + l31]      = f2bf(O0[r] * inv);
        ctx[rowg + 32 + l31] = f2bf(O1[r] * inv);
    }
}

// ---------------------------------------------------------------------------
// Launch. ws layout (bytes): see round-0 comment (unchanged).
// ---------------------------------------------------------------------------
extern "C" void kernel_launch(void* const* d_in, const int* in_sizes, int n_in,
                              void* d_out, int out_size, void* d_ws, size_t ws_size,
                              hipStream_t stream) {
    const float* x    = (const float*)d_in[0];
    const float* mask = (const float*)d_in[1];
    const float* qkvw = (const float*)d_in[2];
    const float* qkvb = (const float*)d_in[3];
    const float* ow   = (const float*)d_in[4];
    const float* ob   = (const float*)d_in[5];
    const float* ln1g = (const float*)d_in[6];
    const float* ln1b = (const float*)d_in[7];
    const float* iw   = (const float*)d_in[8];
    const float* ib   = (const float*)d_in[9];
    const float* o2w  = (const float*)d_in[10];
    const float* o2b  = (const float*)d_in[11];
    const float* ln2g = (const float*)d_in[12];
    const float* ln2b = (const float*)d_in[13];

    char* ws = (char*)d_ws;
    unsigned short* qkvbuf = (unsigned short*)(ws);
    unsigned short* ybuf   = (unsigned short*)(ws + 50331648);
    unsigned short* cbuf   = (unsigned short*)(ws + 67108864);
    float*          x2     = (float*)(ws + 83886080);
    unsigned short* wq     = (unsigned short*)(ws + 117440512);
    unsigned short* wo     = (unsigned short*)(ws + 123731968);
    unsigned short* wi     = (unsigned short*)(ws + 125829120);
    unsigned short* wo2    = (unsigned short*)(ws + 134217728);
    unsigned short* hbuf   = (unsigned short*)(ws);  // overlays qkvbuf+ybuf

    hipFuncSetAttribute(reinterpret_cast<const void*>(attn_kernel),
                        hipFuncAttributeMaxDynamicSharedMemorySize, 65536);
    hipFuncSetAttribute(reinterpret_cast<const void*>(&gemm256<false, true>),
                        hipFuncAttributeMaxDynamicSharedMemorySize, 131072);
    hipFuncSetAttribute(reinterpret_cast<const void*>(&gemm256<true, true>),
                        hipFuncAttributeMaxDynamicSharedMemorySize, 131072);

    wconv_kernel<<<12288, 256, 0, stream>>>(qkvw, ow, iw, o2w, wq, wo, wi, wo2);
    ln_kernel<<<8192, 256, 0, stream>>>(x, ln1g, ln1b, ybuf);
    gemm256<false, true><<<dim3(12, 32), 512, 131072, stream>>>(
        ybuf, wq, qkvb, qkvbuf, 8192, 3072, 1024);
    attn_kernel<<<512, 512, 65536, stream>>>(qkvbuf, mask, cbuf);
    gemm_bt<false, true, false><<<dim3(8, 64), 256, 0, stream>>>(
        cbuf, wo, ob, x, x2, 8192, 1024, 1024);
    ln_kernel<<<8192, 256, 0, stream>>>(x2, ln2g, ln2b, cbuf);
    gemm256<true, true><<<dim3(16, 32), 512, 131072, stream>>>(
        cbuf, wi, ib, hbuf, 8192, 4096, 1024);
    gemm_bt<false, true, false><<<dim3(8, 64), 256, 0, stream>>>(
        hbuf, wo2, o2b, x2, (float*)d_out, 8192, 1024, 4096);
}

// Round 4
// 307.812 us; speedup vs baseline: 1.0150x; 1.0150x over previous
//
#include <hip/hip_runtime.h>

// ---------------------------------------------------------------------------
// LSTransformerEncoderLayer on MI355X (gfx950), round 3.
// Round-3 change: gemm256 pipeline deepened — stage 2 K-tiles ahead (ring of
// 4 half-slots/operand), vmcnt ONLY at p0=vmcnt(6) / p3=vmcnt(8) (never 0 in
// main loop), issue->read distance 4-6 phases (> HBM latency). Ledger:
// in-flight invariant entering tile T = {A1(T),B1(T),A0(T+1),B0(T+1)}.
// gemm_bt/attn/LN/wconv unchanged from round 2.
// ---------------------------------------------------------------------------

using f32x4  = __attribute__((ext_vector_type(4))) float;
using f32x16 = __attribute__((ext_vector_type(16))) float;
using s16x8  = __attribute__((ext_vector_type(8))) short;   // 8 bf16 in 4 VGPRs
using i32x4  = __attribute__((ext_vector_type(4))) int;

__device__ __forceinline__ unsigned short f2bf(float f) {
    unsigned x = __builtin_bit_cast(unsigned, f);
    return (unsigned short)((x + 0x7fffu + ((x >> 16) & 1u)) >> 16);  // RNE
}

#define GLL16(gptr, lptr)                                                     \
    __builtin_amdgcn_global_load_lds(                                         \
        (const __attribute__((address_space(1))) void*)(gptr),                \
        (__attribute__((address_space(3))) void*)(lptr), 16, 0, 0)

#define VMC(N) asm volatile("s_waitcnt vmcnt(" #N ")" ::: "memory")

// ---------------------------------------------------------------------------
// Weight convert: fp32 -> bf16, all four weights in one launch.
// ---------------------------------------------------------------------------
__global__ __launch_bounds__(256) void wconv_kernel(
    const float* __restrict__ w0, const float* __restrict__ w1,
    const float* __restrict__ w2, const float* __restrict__ w3,
    unsigned short* __restrict__ o0, unsigned short* __restrict__ o1,
    unsigned short* __restrict__ o2, unsigned short* __restrict__ o3) {
    long idx = (long)blockIdx.x * 256 + threadIdx.x;  // float4 index
    const float* src;
    unsigned short* dst;
    long rel;
    if (idx < 786432L)        { src = w0; dst = o0; rel = idx; }
    else if (idx < 1048576L)  { src = w1; dst = o1; rel = idx - 786432L; }
    else if (idx < 2097152L)  { src = w2; dst = o2; rel = idx - 1048576L; }
    else                      { src = w3; dst = o3; rel = idx - 2097152L; }
    float4 v = *(const float4*)(src + rel * 4);
    ushort4 o;
    o.x = f2bf(v.x); o.y = f2bf(v.y); o.z = f2bf(v.z); o.w = f2bf(v.w);
    *(ushort4*)(dst + rel * 4) = o;
}

// ---------------------------------------------------------------------------
// LayerNorm: one block per row of 1024 fp32, 256 threads (one float4 each).
// ---------------------------------------------------------------------------
__global__ __launch_bounds__(256) void ln_kernel(
    const float* __restrict__ x, const float* __restrict__ gw,
    const float* __restrict__ bw, unsigned short* __restrict__ y) {
    __shared__ float rbuf[8];
    const int row = blockIdx.x;
    const int t = threadIdx.x;
    const float* xr = x + (size_t)row * 1024;
    float4 v = *(const float4*)(xr + t * 4);
    float s  = v.x + v.y + v.z + v.w;
    float ss = v.x * v.x + v.y * v.y + v.z * v.z + v.w * v.w;
#pragma unroll
    for (int sh = 1; sh < 64; sh <<= 1) {
        s  += __shfl_xor(s, sh, 64);
        ss += __shfl_xor(ss, sh, 64);
    }
    int w = t >> 6;
    if ((t & 63) == 0) { rbuf[w * 2] = s; rbuf[w * 2 + 1] = ss; }
    __syncthreads();
    s  = rbuf[0] + rbuf[2] + rbuf[4] + rbuf[6];
    ss = rbuf[1] + rbuf[3] + rbuf[5] + rbuf[7];
    float mu  = s * (1.f / 1024.f);
    float var = ss * (1.f / 1024.f) - mu * mu;
    float rs  = rsqrtf(var + 1e-5f);
    float4 gv = *(const float4*)(gw + t * 4);
    float4 bv = *(const float4*)(bw + t * 4);
    ushort4 o;
    o.x = f2bf((v.x - mu) * rs * gv.x + bv.x);
    o.y = f2bf((v.y - mu) * rs * gv.y + bv.y);
    o.z = f2bf((v.z - mu) * rs * gv.z + bv.z);
    o.w = f2bf((v.w - mu) * rs * gv.w + bv.w);
    *(ushort4*)(y + (size_t)row * 1024 + t * 4) = o;
}

// ---------------------------------------------------------------------------
// gemm_bt (m97 2-barrier structure) + T1 XCD swizzle. Used for proj & FFN2.
// ---------------------------------------------------------------------------
template <bool RELU, bool RESID, bool OUT_BF16>
__global__ __launch_bounds__(256, 2) void gemm_bt(
    const unsigned short* __restrict__ A, const unsigned short* __restrict__ Bw,
    const float* __restrict__ bias, const float* __restrict__ resid,
    void* __restrict__ Cout, int M, int N, int K) {
    __shared__ char smem[2 * 128 * 64 * 2];
    char* As = smem;
    char* Bs = smem + 128 * 64 * 2;

    const int tid = threadIdx.x;
    const int lane = tid & 63;
    const int w = tid >> 6;
    const int wr = w >> 1, wc = w & 1;
    const int g = lane >> 4;
    const int fr = lane & 15;
    const int nwg = gridDim.x * gridDim.y;
    const int L = blockIdx.y * gridDim.x + blockIdx.x;
    const int swz = (L & 7) * (nwg >> 3) + (L >> 3);
    const int m0 = (swz / gridDim.x) * 128;
    const int n0 = (swz % gridDim.x) * 128;

    f32x4 acc[4][4] = {};

    for (int kt = 0; kt < K; kt += 64) {
#pragma unroll
        for (int c = 0; c < 4; ++c) {
            int lin = (c * 256 + tid) * 16;
            int row = lin >> 7;
            int Lb = lin ^ ((row & 7) << 4);
            int colb = Lb & 127;
            const char* ga = (const char*)A + ((size_t)(m0 + row) * K + kt) * 2 + colb;
            const char* gb = (const char*)Bw + ((size_t)(n0 + row) * K + kt) * 2 + colb;
            GLL16(ga, As + lin);
            GLL16(gb, Bs + lin);
        }
        __syncthreads();
#pragma unroll
        for (int ks = 0; ks < 2; ++ks) {
            s16x8 af[4], bf[4];
#pragma unroll
            for (int mi = 0; mi < 4; ++mi) {
                int row = wr * 64 + mi * 16 + fr;
                int off = (row << 7) + ((ks * 64 + g * 16) ^ ((row & 7) << 4));
                af[mi] = *(const s16x8*)(As + off);
            }
#pragma unroll
            for (int ni = 0; ni < 4; ++ni) {
                int row = wc * 64 + ni * 16 + fr;
                int off = (row << 7) + ((ks * 64 + g * 16) ^ ((row & 7) << 4));
                bf[ni] = *(const s16x8*)(Bs + off);
            }
#pragma unroll
            for (int mi = 0; mi < 4; ++mi)
#pragma unroll
                for (int ni = 0; ni < 4; ++ni)
                    acc[mi][ni] = __builtin_amdgcn_mfma_f32_16x16x32_bf16(
                        af[mi], bf[ni], acc[mi][ni], 0, 0, 0);
        }
        __syncthreads();
    }

    float bv[4];
#pragma unroll
    for (int ni = 0; ni < 4; ++ni) bv[ni] = bias[n0 + wc * 64 + ni * 16 + fr];
#pragma unroll
    for (int mi = 0; mi < 4; ++mi) {
#pragma unroll
        for (int r = 0; r < 4; ++r) {
            int row = m0 + wr * 64 + mi * 16 + g * 4 + r;
#pragma unroll
            for (int ni = 0; ni < 4; ++ni) {
                int col = n0 + wc * 64 + ni * 16 + fr;
                float v = acc[mi][ni][r] + bv[ni];
                if (RELU) v = v > 0.f ? v : 0.f;
                if (RESID) v += resid[(size_t)row * N + col];
                if (OUT_BF16)
                    ((unsigned short*)Cout)[(size_t)row * N + col] = f2bf(v);
                else
                    ((float*)Cout)[(size_t)row * N + col] = v;
            }
        }
    }
}

// ---------------------------------------------------------------------------
// gemm256 v2: deep-pipelined 8-phase-per-2-tiles schedule.
// 256x256 tile, BK=64, 8 waves (2Mx4N), wave tile 128x64, quadrant/phase =
// 16 MFMA. LDS ring: A[4 half-slots][128][64], B same @+65536 (slot of half h
// of tile t = (t&1)*2+h). Stage schedule at tile T: p0->A1(T+1), p1->B1(T+1),
// p2->A0(T+2), p3->B0(T+2). vmcnt(6) at p0, vmcnt(8) at p3 (FIFO drain:
// p0 drains {A1,B1}(T), p3 drains {A0,B0}(T+1)). Tails: (6,4) then (0,-).
// ---------------------------------------------------------------------------
template <bool RELU, bool OUT_BF16>
__global__ __launch_bounds__(512, 2) void gemm256(
    const unsigned short* __restrict__ A, const unsigned short* __restrict__ Bw,
    const float* __restrict__ bias, void* __restrict__ Cout,
    int M, int N, int K) {
    extern __shared__ char lds[];

    const int tid = threadIdx.x;
    const int lane = tid & 63;
    const int w = tid >> 6;
    const int wm = w >> 2, wn = w & 3;
    const int g = lane >> 4, fr = lane & 15;

    const int nwg = gridDim.x * gridDim.y;
    const int L = blockIdx.y * gridDim.x + blockIdx.x;
    const int swz = (L & 7) * (nwg >> 3) + (L >> 3);
    const int m0 = (swz / gridDim.x) * 256;
    const int n0 = (swz % gridDim.x) * 256;

    const int NT = K >> 6;

    auto stageA = [&](int t, int h) {
        char* dst = lds + (t & 1) * 32768 + h * 16384;
#pragma unroll
        for (int c2 = 0; c2 < 2; ++c2) {
            int lin = (c2 * 512 + tid) * 16;
            int row = lin >> 7;
            int colb = (lin & 127) ^ ((row & 7) << 4);
            GLL16((const char*)A + ((size_t)(m0 + h * 128 + row) * K + t * 64) * 2 + colb,
                  dst + lin);
        }
    };
    auto stageB = [&](int t, int h) {
        char* dst = lds + 65536 + (t & 1) * 32768 + h * 16384;
#pragma unroll
        for (int c2 = 0; c2 < 2; ++c2) {
            int lin = (c2 * 512 + tid) * 16;
            int row = lin >> 7;
            int colb = (lin & 127) ^ ((row & 7) << 4);
            GLL16((const char*)Bw + ((size_t)(n0 + h * 128 + row) * K + t * 64) * 2 + colb,
                  dst + lin);
        }
    };

    f32x4 acc[2][4][2][2] = {};  // [ha][mi2][hb][ni2]
    s16x8 af[4][2];
    s16x8 bf[2][2];

    auto loadA = [&](const char* Ab, int ha) {
#pragma unroll
        for (int mi2 = 0; mi2 < 4; ++mi2) {
            int row = ha * 128 + wm * 64 + mi2 * 16 + fr;
#pragma unroll
            for (int ks = 0; ks < 2; ++ks)
                af[mi2][ks] = *(const s16x8*)(Ab + (row << 7) +
                               ((ks * 64 + g * 16) ^ ((row & 7) << 4)));
        }
    };
    auto loadB = [&](const char* Bb, int hb) {
#pragma unroll
        for (int ni2 = 0; ni2 < 2; ++ni2) {
            int row = hb * 128 + wn * 32 + ni2 * 16 + fr;
#pragma unroll
            for (int ks = 0; ks < 2; ++ks)
                bf[ni2][ks] = *(const s16x8*)(Bb + (row << 7) +
                               ((ks * 64 + g * 16) ^ ((row & 7) << 4)));
        }
    };

#define MFMAQ(HA, HB)                                                         \
    __builtin_amdgcn_s_barrier();                                             \
    asm volatile("s_waitcnt lgkmcnt(0)" ::: "memory");                        \
    __builtin_amdgcn_sched_barrier(0);                                        \
    __builtin_amdgcn_s_setprio(1);                                            \
    _Pragma("unroll")                                                         \
    for (int mi2 = 0; mi2 < 4; ++mi2)                                         \
        _Pragma("unroll")                                                     \
        for (int ni2 = 0; ni2 < 2; ++ni2)                                     \
            _Pragma("unroll")                                                 \
            for (int ks = 0; ks < 2; ++ks)                                    \
                acc[HA][mi2][HB][ni2] =                                       \
                    __builtin_amdgcn_mfma_f32_16x16x32_bf16(                  \
                        af[mi2][ks], bf[ni2][ks], acc[HA][mi2][HB][ni2],      \
                        0, 0, 0);                                             \
    __builtin_amdgcn_s_setprio(0);                                            \
    __builtin_amdgcn_s_barrier();

    // prologue: 6 halves (12 loads); vmcnt(8) drains A0(0),B0(0).
    // In-flight invariant entering tile 0: {A1(0),B1(0),A0(1),B0(1)}.
    stageA(0, 0); stageB(0, 0); stageA(0, 1); stageB(0, 1);
    stageA(1, 0); stageB(1, 0);
    VMC(8);
    __builtin_amdgcn_s_barrier();

    for (int t = 0; t < NT - 2; ++t) {
        char* Ab = lds + (t & 1) * 32768;
        char* Bb = lds + 65536 + (t & 1) * 32768;
        loadA(Ab, 0); loadB(Bb, 0); stageA(t + 1, 1); VMC(6); MFMAQ(0, 0);
        loadB(Bb, 1);               stageB(t + 1, 1);         MFMAQ(0, 1);
        loadA(Ab, 1); loadB(Bb, 0); stageA(t + 2, 0);         MFMAQ(1, 0);
        loadB(Bb, 1);               stageB(t + 2, 0); VMC(8); MFMAQ(1, 1);
    }
    {   // tile NT-2: no t+2 stages; p3 drains {A0,B0}(NT-1) via vmcnt(4)
        const int t = NT - 2;
        char* Ab = lds + (t & 1) * 32768;
        char* Bb = lds + 65536 + (t & 1) * 32768;
        loadA(Ab, 0); loadB(Bb, 0); stageA(t + 1, 1); VMC(6); MFMAQ(0, 0);
        loadB(Bb, 1);               stageB(t + 1, 1);         MFMAQ(0, 1);
        loadA(Ab, 1); loadB(Bb, 0);                           MFMAQ(1, 0);
        loadB(Bb, 1);                                 VMC(4); MFMAQ(1, 1);
    }
    {   // tile NT-1: drain everything at p0
        const int t = NT - 1;
        char* Ab = lds + (t & 1) * 32768;
        char* Bb = lds + 65536 + (t & 1) * 32768;
        loadA(Ab, 0); loadB(Bb, 0);                   VMC(0); MFMAQ(0, 0);
        loadB(Bb, 1);                                         MFMAQ(0, 1);
        loadA(Ab, 1); loadB(Bb, 0);                           MFMAQ(1, 0);
        loadB(Bb, 1);                                         MFMAQ(1, 1);
    }
#undef MFMAQ

    // epilogue: bias (+relu), store
#pragma unroll
    for (int ha = 0; ha < 2; ++ha)
#pragma unroll
        for (int mi2 = 0; mi2 < 4; ++mi2)
#pragma unroll
            for (int r = 0; r < 4; ++r) {
                int row = m0 + ha * 128 + wm * 64 + mi2 * 16 + g * 4 + r;
#pragma unroll
                for (int hb = 0; hb < 2; ++hb)
#pragma unroll
                    for (int ni2 = 0; ni2 < 2; ++ni2) {
                        int col = n0 + hb * 128 + wn * 32 + ni2 * 16 + fr;
                        float v = acc[ha][mi2][hb][ni2][r] + bias[col];
                        if (RELU) v = v > 0.f ? v : 0.f;
                        if (OUT_BF16)
                            ((unsigned short*)Cout)[(size_t)row * N + col] = f2bf(v);
                        else
                            ((float*)Cout)[(size_t)row * N + col] = v;
                    }
            }
}

// ---------------------------------------------------------------------------
// Fused attention v2 (unchanged from round 1).
// ---------------------------------------------------------------------------
__global__ __launch_bounds__(512, 2) void attn_kernel(
    const unsigned short* __restrict__ qkv, const float* __restrict__ mask,
    unsigned short* __restrict__ ctx) {
    extern __shared__ char smem[];

    const int tid = threadIdx.x;
    const int lane = tid & 63;
    const int w = tid >> 6;
    const int l31 = lane & 31;
    const int hi = lane >> 5;
    const int bh = blockIdx.x >> 1;
    const int b = bh >> 4, h = bh & 15;
    const int qt = (blockIdx.x & 1) * 256 + w * 32;

    const size_t rstr = 3072;
    const unsigned short* qbase = qkv + (size_t)b * 512 * rstr + h * 64;
    const unsigned short* kbase = qbase + 1024;
    const unsigned short* vbase = qbase + 2048;
    const float* mrow = mask + b * 512;

    s16x8 qf[4];
#pragma unroll
    for (int kc = 0; kc < 4; ++kc)
        qf[kc] = *(const s16x8*)(qbase + (size_t)(qt + l31) * rstr + kc * 16 + hi * 8);

    f32x16 O0 = {}, O1 = {};
    float m = -3e38f, l = 0.f;
    const int bpbase = 36 * hi * 4;

    auto stage = [&](int kt, int bufsel) {
        char* Kb = smem + bufsel * 16384;
        char* Vb = smem + 32768 + bufsel * 16384;
#pragma unroll
        for (int c = 0; c < 2; ++c) {
            int lin = (c * 512 + tid) * 16;
            int row = lin >> 7;
            int colb = (lin & 127) ^ ((row & 7) << 4);
            GLL16((const char*)kbase + (size_t)(kt * 128 + row) * rstr * 2 + colb,
                  Kb + lin);
        }
        int s = tid & 127, dg = tid >> 7;
        const unsigned short* vsrc = vbase + (size_t)(kt * 128 + s) * rstr + dg * 16;
        union { i32x4 v; unsigned short u[8]; } v0, v1;
        v0.v = *(const i32x4*)vsrc;
        v1.v = *(const i32x4*)(vsrc + 8);
#pragma unroll
        for (int j = 0; j < 8; ++j) {
            int d = dg * 16 + j;
            *(unsigned short*)(Vb + d * 256 + ((s * 2) ^ ((d & 15) << 4))) = v0.u[j];
        }
#pragma unroll
        for (int j = 0; j < 8; ++j) {
            int d = dg * 16 + 8 + j;
            *(unsigned short*)(Vb + d * 256 + ((s * 2) ^ ((d & 15) << 4))) = v1.u[j];
        }
    };

    const float C   = 0.18033688f;   // log2e / sqrt(64)
    const float L2E = 1.44269504f;

    stage(0, 0);
    __syncthreads();

    for (int kt = 0; kt < 4; ++kt) {
        const int cur = kt & 1;
        if (kt < 3) stage(kt + 1, cur ^ 1);
        char* Kb = smem + cur * 16384;
        char* Vb = smem + 32768 + cur * 16384;
        const int swzk = (l31 & 7) << 4;

        f32x16 sc[4];
#pragma unroll
        for (int t = 0; t < 4; ++t) {
            f32x16 a = {};
#pragma unroll
            for (int kc = 0; kc < 4; ++kc) {
                s16x8 kf = *(const s16x8*)(Kb + (32 * t + l31) * 128 +
                                           ((kc * 32 + hi * 16) ^ swzk));
                a = __builtin_amdgcn_mfma_f32_32x32x16_bf16(kf, qf[kc], a, 0, 0, 0);
            }
            sc[t] = a;
        }

        float tm = -3e38f;
#pragma unroll
        for (int t = 0; t < 4; ++t) {
#pragma unroll
            for (int k2 = 0; k2 < 4; ++k2) {
                f32x4 mk = *(const f32x4*)(mrow + kt * 128 + 32 * t + 8 * k2 + 4 * hi);
#pragma unroll
                for (int i = 0; i < 4; ++i) {
                    float v = sc[t][4 * k2 + i] * C + mk[i] * L2E;
                    sc[t][4 * k2 + i] = v;
                    tm = fmaxf(tm, v);
                }
            }
        }
        tm = fmaxf(tm, __shfl_xor(tm, 32, 64));

        if (__any(tm > m + 11.0f)) {
            float mn = fmaxf(m, tm);
            float fac = exp2f(m - mn);
            m = mn;
            l *= fac;
            int fi = __float_as_int(fac);
#pragma unroll
            for (int r = 0; r < 16; ++r) {
                int q2 = (r & 3) + 8 * (r >> 2);
                float fq = __int_as_float(
                    __builtin_amdgcn_ds_bpermute(bpbase + q2 * 4, fi));
                O0[r] *= fq;
                O1[r] *= fq;
            }
        }

        float ts = 0.f;
#pragma unroll
        for (int t = 0; t < 4; ++t)
#pragma unroll
            for (int r = 0; r < 16; ++r) {
                float p = exp2f(sc[t][r] - m);
                sc[t][r] = p;
                ts += p;
            }
        ts += __shfl_xor(ts, 32, 64);
        l += ts;

        unsigned pk01[4][4], pk23[4][4];
#pragma unroll
        for (int t = 0; t < 4; ++t)
#pragma unroll
            for (int k = 0; k < 4; ++k) {
                unsigned r0, r1;
                asm("v_cvt_pk_bf16_f32 %0, %1, %2"
                    : "=v"(r0) : "v"(sc[t][4 * k]), "v"(sc[t][4 * k + 1]));
                asm("v_cvt_pk_bf16_f32 %0, %1, %2"
                    : "=v"(r1) : "v"(sc[t][4 * k + 2]), "v"(sc[t][4 * k + 3]));
                pk01[t][k] = r0;
                pk23[t][k] = r1;
            }

#pragma unroll
        for (int t = 0; t < 4; ++t)
#pragma unroll
            for (int cc = 0; cc < 2; ++cc) {
                unsigned a0 = pk01[t][2 * cc], b0 = pk01[t][2 * cc + 1];
                unsigned c0 = pk23[t][2 * cc], d0 = pk23[t][2 * cc + 1];
                asm("v_permlane32_swap_b32 %0, %1" : "+v"(a0), "+v"(b0));
                asm("v_permlane32_swap_b32 %0, %1" : "+v"(c0), "+v"(d0));
                union { unsigned u[4]; s16x8 v; } pf;
                pf.u[0] = a0;
                pf.u[1] = c0;
                pf.u[2] = b0;
                pf.u[3] = d0;
                const int kc = 2 * t + cc;
                {
                    int row = l31;
                    s16x8 vf = *(const s16x8*)(Vb + row * 256 +
                               ((kc * 32 + hi * 16) ^ ((row & 15) << 4)));
                    O0 = __builtin_amdgcn_mfma_f32_32x32x16_bf16(pf.v, vf, O0, 0, 0, 0);
                }
                {
                    int row = 32 + l31;
                    s16x8 vf = *(const s16x8*)(Vb + row * 256 +
                               ((kc * 32 + hi * 16) ^ ((row & 15) << 4)));
                    O1 = __builtin_amdgcn_mfma_f32_32x32x16_bf16(pf.v, vf, O1, 0, 0, 0);
                }
            }
        __syncthreads();
    }

    const int li = __float_as_int(l);
#pragma unroll
    for (int r = 0; r < 16; ++r) {
        int q2 = (r & 3) + 8 * (r >> 2);
        float lq = __int_as_float(__builtin_amdgcn_ds_bpermute(bpbase + q2 * 4, li));
        float inv = 1.f / lq;
        size_t rowg = (size_t)(b * 512 + qt + q2 + 4 * hi) * 1024 + h * 64;
        ctx[rowg + l31]      = f2bf(O0[r] * inv);
        ctx[rowg + 32 + l31] = f2bf(O1[r] * inv);
    }
}

// ---------------------------------------------------------------------------
// Launch. ws layout (bytes): see round-0 comment (unchanged).
// ---------------------------------------------------------------------------
extern "C" void kernel_launch(void* const* d_in, const int* in_sizes, int n_in,
                              void* d_out, int out_size, void* d_ws, size_t ws_size,
                              hipStream_t stream) {
    const float* x    = (const float*)d_in[0];
    const float* mask = (const float*)d_in[1];
    const float* qkvw = (const float*)d_in[2];
    const float* qkvb = (const float*)d_in[3];
    const float* ow   = (const float*)d_in[4];
    const float* ob   = (const float*)d_in[5];
    const float* ln1g = (const float*)d_in[6];
    const float* ln1b = (const float*)d_in[7];
    const float* iw   = (const float*)d_in[8];
    const float* ib   = (const float*)d_in[9];
    const float* o2w  = (const float*)d_in[10];
    const float* o2b  = (const float*)d_in[11];
    const float* ln2g = (const float*)d_in[12];
    const float* ln2b = (const float*)d_in[13];

    char* ws = (char*)d_ws;
    unsigned short* qkvbuf = (unsigned short*)(ws);
    unsigned short* ybuf   = (unsigned short*)(ws + 50331648);
    unsigned short* cbuf   = (unsigned short*)(ws + 67108864);
    float*          x2     = (float*)(ws + 83886080);
    unsigned short* wq     = (unsigned short*)(ws + 117440512);
    unsigned short* wo     = (unsigned short*)(ws + 123731968);
    unsigned short* wi     = (unsigned short*)(ws + 125829120);
    unsigned short* wo2    = (unsigned short*)(ws + 134217728);
    unsigned short* hbuf   = (unsigned short*)(ws);  // overlays qkvbuf+ybuf

    hipFuncSetAttribute(reinterpret_cast<const void*>(attn_kernel),
                        hipFuncAttributeMaxDynamicSharedMemorySize, 65536);
    hipFuncSetAttribute(reinterpret_cast<const void*>(&gemm256<false, true>),
                        hipFuncAttributeMaxDynamicSharedMemorySize, 131072);
    hipFuncSetAttribute(reinterpret_cast<const void*>(&gemm256<true, true>),
                        hipFuncAttributeMaxDynamicSharedMemorySize, 131072);

    wconv_kernel<<<12288, 256, 0, stream>>>(qkvw, ow, iw, o2w, wq, wo, wi, wo2);
    ln_kernel<<<8192, 256, 0, stream>>>(x, ln1g, ln1b, ybuf);
    gemm256<false, true><<<dim3(12, 32), 512, 131072, stream>>>(
        ybuf, wq, qkvb, qkvbuf, 8192, 3072, 1024);
    attn_kernel<<<512, 512, 65536, stream>>>(qkvbuf, mask, cbuf);
    gemm_bt<false, true, false><<<dim3(8, 64), 256, 0, stream>>>(
        cbuf, wo, ob, x, x2, 8192, 1024, 1024);
    ln_kernel<<<8192, 256, 0, stream>>>(x2, ln2g, ln2b, cbuf);
    gemm256<true, true><<<dim3(16, 32), 512, 131072, stream>>>(
        cbuf, wi, ib, hbuf, 8192, 4096, 1024);
    gemm_bt<false, true, false><<<dim3(8, 64), 256, 0, stream>>>(
        hbuf, wo2, o2b, x2, (float*)d_out, 8192, 1024, 4096);
}